// Round 4
// baseline (145574.414 us; speedup 1.0000x reference)
//
#include <hip/hip_runtime.h>
#include <math.h>

// Problem constants
#define B 256
#define Hh 512
#define S 200
#define T 200
#define VOC 512
#define G3 1536
#define PAD 36
#define NBLK 512
#define NTHR 256

// LDS arena offsets (bytes). Max concurrent use = P3: 30,464 B (2 blocks/CU
// under ROCm's 64 KB LDS occupancy accounting -> 512-block coop launch legal).
#define HT_OFF 0        // [32][68] f32 h/ctx tile (8704 B)
#define XT_OFF 8704     // [32][68] f32 x tile    (8704 B)
#define WA_OFF 17408    // [24][68] f32 W tile A  (6528 B)
#define WB_OFF 23936    // [24][68] f32 W tile B  (6528 B)
#define SCX_OFF 0       // [4][512] f32 attention partials (8192 B)
#define SML_OFF 8192    // [8] double m/l (64 B)
#define REDF_OFF 0      // [256] f32
#define REDD_OFF 1024   // [256] double
#define REDI_OFF 3072   // [256] int
#define ARENA_BYTES 30720

// fp64 helpers: inner-product math in double, tensor boundaries quantized fp32.
struct d4 { double x, y, z, w; };
__device__ __forceinline__ d4 tod4(const float4 a) {
    d4 r; r.x = a.x; r.y = a.y; r.z = a.z; r.w = a.w; return r;
}
__device__ __forceinline__ double dotd(const d4& a, const d4& b) {
    return a.x * b.x + a.y * b.y + a.z * b.z + a.w * b.w;
}
__device__ __forceinline__ double sigd(double x) { return 1.0 / (1.0 + exp(-x)); }

// ---------------------------------------------------------------------------
// Group barrier: monotonic counter, agent-scope atomics. nb = participants.
// ---------------------------------------------------------------------------
__device__ __forceinline__ void gsync(unsigned* bar, unsigned* tgt, unsigned nb) {
    __threadfence();
    __syncthreads();
    *tgt += nb;
    if (threadIdx.x == 0) {
        __hip_atomic_fetch_add(bar, 1u, __ATOMIC_RELEASE, __HIP_MEMORY_SCOPE_AGENT);
        while (__hip_atomic_load(bar, __ATOMIC_ACQUIRE, __HIP_MEMORY_SCOPE_AGENT) < *tgt)
            __builtin_amdgcn_s_sleep(2);
    }
    __syncthreads();
    __threadfence();
}

// ===========================================================================
// Round-2 proven kernels (precompute + fallback path)
// ===========================================================================
__global__ __launch_bounds__(256) void gemm_at(
    const float* __restrict__ A,
    const float* __restrict__ W, int ldw, int woff,
    const float* __restrict__ bias,
    const float* __restrict__ tab, const int* __restrict__ tseq, int t,
    float* __restrict__ C, int ldc, int act)
{
    __shared__ float As[32][PAD];
    __shared__ float Ws[32][PAD];
    const int tid = threadIdx.x;
    const int tx = tid & 15, ty = tid >> 4;
    const int j0 = blockIdx.x * 32, m0 = blockIdx.y * 32;
    const int lr = tid >> 3, lc = (tid & 7) * 4;

    double acc00 = 0.0, acc01 = 0.0, acc10 = 0.0, acc11 = 0.0;

    for (int k0 = 0; k0 < 512; k0 += 32) {
        float4 av = *(const float4*)(A + (size_t)(m0 + lr) * 512 + k0 + lc);
        float4 wv = *(const float4*)(W + (size_t)(j0 + lr) * ldw + woff + k0 + lc);
        __syncthreads();
        *(float4*)&As[lr][lc] = av;
        *(float4*)&Ws[lr][lc] = wv;
        __syncthreads();
#pragma unroll
        for (int kk = 0; kk < 32; kk += 4) {
            d4 a0 = tod4(*(const float4*)&As[ty][kk]);
            d4 a1 = tod4(*(const float4*)&As[ty + 16][kk]);
            d4 b0 = tod4(*(const float4*)&Ws[tx][kk]);
            d4 b1 = tod4(*(const float4*)&Ws[tx + 16][kk]);
            acc00 += dotd(a0, b0);
            acc01 += dotd(a0, b1);
            acc10 += dotd(a1, b0);
            acc11 += dotd(a1, b1);
        }
    }
    const int ms[2] = { m0 + ty, m0 + ty + 16 };
    const int js[2] = { j0 + tx, j0 + tx + 16 };
    double accs[2][2] = { { acc00, acc01 }, { acc10, acc11 } };
#pragma unroll
    for (int mi = 0; mi < 2; ++mi)
#pragma unroll
        for (int ji = 0; ji < 2; ++ji) {
            int m = ms[mi], j = js[ji];
            double v = accs[mi][ji];
            if (bias) v += (double)bias[j];
            if (tab) {
                int tok = (t == 0) ? 1 : tseq[(t - 1) * B + m];
                v += (double)tab[(size_t)tok * 512 + j];
            }
            if (act == 1) v = v > 0.0 ? v : 0.0;
            else if (act == 2) v = tanh(v);
            C[(size_t)m * ldc + j] = (float)v;
        }
}

__global__ __launch_bounds__(256) void enc_step(
    const float* __restrict__ h_in, float* __restrict__ h_out,
    const float* __restrict__ gi_tab, const int* __restrict__ iseq,
    const int* __restrict__ ilen, const float* __restrict__ Whh,
    const float* __restrict__ bhh, int s, float* __restrict__ enc_out)
{
    __shared__ float Hs[32][PAD];
    __shared__ float Ws[48][PAD];
    const int tid = threadIdx.x;
    const int tx = tid & 15, ty = tid >> 4;
    const int j0 = blockIdx.x * 16, b0 = blockIdx.y * 32;
    const int lr = tid >> 3, lc = (tid & 7) * 4;

    double ar0 = 0.0, az0 = 0.0, an0 = 0.0;
    double ar1 = 0.0, az1 = 0.0, an1 = 0.0;

    for (int k0 = 0; k0 < 512; k0 += 32) {
        float4 hv = *(const float4*)(h_in + (size_t)(b0 + lr) * 512 + k0 + lc);
        int g0 = lr >> 4, jj0 = lr & 15;
        float4 wv0 = *(const float4*)(Whh + (size_t)(g0 * 512 + j0 + jj0) * 512 + k0 + lc);
        float4 wv1;
        if (tid < 128) {
            int jj1 = lr & 15;
            wv1 = *(const float4*)(Whh + (size_t)(2 * 512 + j0 + jj1) * 512 + k0 + lc);
        }
        __syncthreads();
        *(float4*)&Hs[lr][lc] = hv;
        *(float4*)&Ws[lr][lc] = wv0;
        if (tid < 128) *(float4*)&Ws[32 + lr][lc] = wv1;
        __syncthreads();
#pragma unroll
        for (int kk = 0; kk < 32; kk += 4) {
            d4 a0 = tod4(*(const float4*)&Hs[ty][kk]);
            d4 a1 = tod4(*(const float4*)&Hs[ty + 16][kk]);
            d4 wr = tod4(*(const float4*)&Ws[tx][kk]);
            d4 wz = tod4(*(const float4*)&Ws[16 + tx][kk]);
            d4 wn = tod4(*(const float4*)&Ws[32 + tx][kk]);
            ar0 += dotd(a0, wr); az0 += dotd(a0, wz); an0 += dotd(a0, wn);
            ar1 += dotd(a1, wr); az1 += dotd(a1, wz); an1 += dotd(a1, wn);
        }
    }
    const int j = j0 + tx;
    const double br = (double)bhh[j], bz = (double)bhh[512 + j], bn = (double)bhh[1024 + j];
    double gr[2] = { ar0, ar1 }, gz[2] = { az0, az1 }, gn[2] = { an0, an1 };
#pragma unroll
    for (int bb = 0; bb < 2; ++bb) {
        int b = b0 + ty + 16 * bb;
        int tok = iseq[s * B + b];
        const float* gi = gi_tab + (size_t)tok * G3;
        double r = sigd((double)gi[j] + gr[bb] + br);
        double z = sigd((double)gi[512 + j] + gz[bb] + bz);
        double n = tanh((double)gi[1024 + j] + r * (gn[bb] + bn));
        float hold = h_in[(size_t)b * 512 + j];
        float hn = (float)((1.0 - z) * n + z * (double)hold);
        bool msk = s < ilen[b];
        float hnew = msk ? hn : hold;
        h_out[(size_t)b * 512 + j] = hnew;
        enc_out[((size_t)s * B + b) * 512 + j] = msk ? hnew : 0.f;
    }
}

__global__ __launch_bounds__(256) void dec_gru(
    const float* __restrict__ x, const float* __restrict__ h_in,
    const float* __restrict__ Wih, const float* __restrict__ Whh,
    const float* __restrict__ bih, const float* __restrict__ bhh,
    float* __restrict__ h_out)
{
    __shared__ float Xs[32][PAD];
    __shared__ float Hs[32][PAD];
    __shared__ float Wi[48][PAD];
    __shared__ float Wh[48][PAD];
    const int tid = threadIdx.x;
    const int tx = tid & 15, ty = tid >> 4;
    const int j0 = blockIdx.x * 16, b0 = blockIdx.y * 32;
    const int lr = tid >> 3, lc = (tid & 7) * 4;

    double air0 = 0, aiz0 = 0, ain0 = 0, ahr0 = 0, ahz0 = 0, ahn0 = 0;
    double air1 = 0, aiz1 = 0, ain1 = 0, ahr1 = 0, ahz1 = 0, ahn1 = 0;

    for (int k0 = 0; k0 < 512; k0 += 32) {
        float4 xv = *(const float4*)(x + (size_t)(b0 + lr) * 512 + k0 + lc);
        float4 hv = *(const float4*)(h_in + (size_t)(b0 + lr) * 512 + k0 + lc);
        int g0 = lr >> 4, jj0 = lr & 15;
        float4 wi0 = *(const float4*)(Wih + (size_t)(g0 * 512 + j0 + jj0) * 512 + k0 + lc);
        float4 wh0 = *(const float4*)(Whh + (size_t)(g0 * 512 + j0 + jj0) * 512 + k0 + lc);
        float4 wi1, wh1;
        if (tid < 128) {
            int jj1 = lr & 15;
            wi1 = *(const float4*)(Wih + (size_t)(2 * 512 + j0 + jj1) * 512 + k0 + lc);
            wh1 = *(const float4*)(Whh + (size_t)(2 * 512 + j0 + jj1) * 512 + k0 + lc);
        }
        __syncthreads();
        *(float4*)&Xs[lr][lc] = xv;
        *(float4*)&Hs[lr][lc] = hv;
        *(float4*)&Wi[lr][lc] = wi0;
        *(float4*)&Wh[lr][lc] = wh0;
        if (tid < 128) { *(float4*)&Wi[32 + lr][lc] = wi1; *(float4*)&Wh[32 + lr][lc] = wh1; }
        __syncthreads();
#pragma unroll
        for (int kk = 0; kk < 32; kk += 4) {
            d4 x0 = tod4(*(const float4*)&Xs[ty][kk]);
            d4 x1 = tod4(*(const float4*)&Xs[ty + 16][kk]);
            d4 h0 = tod4(*(const float4*)&Hs[ty][kk]);
            d4 h1 = tod4(*(const float4*)&Hs[ty + 16][kk]);
            d4 wir = tod4(*(const float4*)&Wi[tx][kk]);
            d4 wiz = tod4(*(const float4*)&Wi[16 + tx][kk]);
            d4 win = tod4(*(const float4*)&Wi[32 + tx][kk]);
            d4 whr = tod4(*(const float4*)&Wh[tx][kk]);
            d4 whz = tod4(*(const float4*)&Wh[16 + tx][kk]);
            d4 whn = tod4(*(const float4*)&Wh[32 + tx][kk]);
            air0 += dotd(x0, wir); aiz0 += dotd(x0, wiz); ain0 += dotd(x0, win);
            ahr0 += dotd(h0, whr); ahz0 += dotd(h0, whz); ahn0 += dotd(h0, whn);
            air1 += dotd(x1, wir); aiz1 += dotd(x1, wiz); ain1 += dotd(x1, win);
            ahr1 += dotd(h1, whr); ahz1 += dotd(h1, whz); ahn1 += dotd(h1, whn);
        }
    }
    const int j = j0 + tx;
    const double bir = (double)bih[j], biz = (double)bih[512 + j], bin = (double)bih[1024 + j];
    const double bhr = (double)bhh[j], bhz = (double)bhh[512 + j], bhn = (double)bhh[1024 + j];
    double ir[2] = { air0, air1 }, iz[2] = { aiz0, aiz1 }, in_[2] = { ain0, ain1 };
    double hr[2] = { ahr0, ahr1 }, hz[2] = { ahz0, ahz1 }, hn_[2] = { ahn0, ahn1 };
#pragma unroll
    for (int bb = 0; bb < 2; ++bb) {
        int b = b0 + ty + 16 * bb;
        double r = sigd(ir[bb] + bir + hr[bb] + bhr);
        double z = sigd(iz[bb] + biz + hz[bb] + bhz);
        double n = tanh(in_[bb] + bin + r * (hn_[bb] + bhn));
        float hold = h_in[(size_t)b * 512 + j];
        h_out[(size_t)b * 512 + j] = (float)((1.0 - z) * n + z * (double)hold);
    }
}

__global__ __launch_bounds__(256) void attn_step(
    const float* __restrict__ enc_out, const float* __restrict__ ah,
    float* __restrict__ ctx)
{
    const int b = blockIdx.x;
    const int tid = threadIdx.x;
    const int wave = tid >> 6, lane = tid & 63;

    const d4 a1 = tod4(*(const float4*)(ah + (size_t)b * 512 + lane * 4));
    const d4 a2 = tod4(*(const float4*)(ah + (size_t)b * 512 + 256 + lane * 4));

    double m = -INFINITY, l = 0.0;
    d4 c1 = { 0, 0, 0, 0 }, c2 = { 0, 0, 0, 0 };

    for (int s = wave; s < S; s += 4) {
        const float* row = enc_out + ((size_t)s * B + b) * 512;
        d4 e1 = tod4(*(const float4*)(row + lane * 4));
        d4 e2 = tod4(*(const float4*)(row + 256 + lane * 4));
        double p = dotd(e1, a1) + dotd(e2, a2);
#pragma unroll
        for (int off = 32; off >= 1; off >>= 1) p += __shfl_xor(p, off, 64);
        double mn = fmax(m, p);
        double sc = exp(m - mn);
        double w = exp(p - mn);
        l = l * sc + w;
        c1.x = c1.x * sc + w * e1.x; c1.y = c1.y * sc + w * e1.y;
        c1.z = c1.z * sc + w * e1.z; c1.w = c1.w * sc + w * e1.w;
        c2.x = c2.x * sc + w * e2.x; c2.y = c2.y * sc + w * e2.y;
        c2.z = c2.z * sc + w * e2.z; c2.w = c2.w * sc + w * e2.w;
        m = mn;
    }

    __shared__ double sm[4], sl[4];
    __shared__ double scx[4][512];
    if (lane == 0) { sm[wave] = m; sl[wave] = l; }
    scx[wave][lane * 4 + 0] = c1.x; scx[wave][lane * 4 + 1] = c1.y;
    scx[wave][lane * 4 + 2] = c1.z; scx[wave][lane * 4 + 3] = c1.w;
    scx[wave][256 + lane * 4 + 0] = c2.x; scx[wave][256 + lane * 4 + 1] = c2.y;
    scx[wave][256 + lane * 4 + 2] = c2.z; scx[wave][256 + lane * 4 + 3] = c2.w;
    __syncthreads();

    double M = fmax(fmax(sm[0], sm[1]), fmax(sm[2], sm[3]));
    double w0 = exp(sm[0] - M), w1 = exp(sm[1] - M);
    double w2 = exp(sm[2] - M), w3 = exp(sm[3] - M);
    double L = sl[0] * w0 + sl[1] * w1 + sl[2] * w2 + sl[3] * w3;

    for (int j = tid; j < 512; j += 256) {
        double v = scx[0][j] * w0 + scx[1][j] * w1 + scx[2][j] * w2 + scx[3][j] * w3;
        ctx[(size_t)b * 512 + j] = (float)(v / L);
    }
}

__global__ __launch_bounds__(256) void softmax_loss(
    const float* __restrict__ logits, const int* __restrict__ target,
    int t, float* __restrict__ nll, float* __restrict__ inference)
{
    const int b = blockIdx.x, tid = threadIdx.x;
    const float l0 = logits[(size_t)b * 512 + tid];
    const float l1 = logits[(size_t)b * 512 + 256 + tid];

    __shared__ float sv[256];
    sv[tid] = fmaxf(l0, l1);
    __syncthreads();
    for (int off = 128; off > 0; off >>= 1) {
        if (tid < off) sv[tid] = fmaxf(sv[tid], sv[tid + off]);
        __syncthreads();
    }
    const double mx = (double)sv[0];
    __syncthreads();

    __shared__ double sd[256];
    const double e0 = exp((double)l0 - mx);
    const double e1 = exp((double)l1 - mx);
    sd[tid] = e0 + e1;
    __syncthreads();
    for (int off = 128; off > 0; off >>= 1) {
        if (tid < off) sd[tid] += sd[tid + off];
        __syncthreads();
    }
    const double Z = sd[0];
    __syncthreads();

    const float p0 = (float)(e0 / Z);
    const float p1 = (float)(e1 / Z);
    float v; int idx;
    if (p0 >= p1) { v = p0; idx = tid; } else { v = p1; idx = 256 + tid; }

    __shared__ float pv[256];
    __shared__ int pi[256];
    pv[tid] = v; pi[tid] = idx;
    __syncthreads();
    for (int off = 128; off > 0; off >>= 1) {
        if (tid < off) {
            float ov = pv[tid + off]; int oi = pi[tid + off];
            if (ov > pv[tid] || (ov == pv[tid] && oi < pi[tid])) { pv[tid] = ov; pi[tid] = oi; }
        }
        __syncthreads();
    }
    if (tid == 0) {
        int tgt = target[t * B + b];
        float pt = (float)(exp((double)logits[(size_t)b * 512 + tgt] - mx) / Z);
        pt = fmaxf(pt, 1e-10f);
        nll[t * B + b] = (float)(-log((double)pt));
        inference[t * B + b] = (float)pi[0];
    }
}

__global__ __launch_bounds__(256) void finalize_k(
    const float* __restrict__ nll, const float* __restrict__ inference,
    const int* __restrict__ target, float* __restrict__ out3)
{
    const int tid = threadIdx.x;
    int wrong = 0;
    double match = 0.0;
    const int b = tid;
    for (int t = 0; t < T; ++t) {
        float inf = inference[t * B + b];
        float tg = (float)target[t * B + b];
        bool ok = (inf == tg);
        match += ok ? 1.0 : 0.0;
        wrong |= !ok;
    }
    double lsum = 0.0;
    for (int i = tid; i < T * B; i += 256) lsum += (double)nll[i];

    __shared__ double sl[256], sm_[256], sa[256];
    sl[tid] = lsum; sm_[tid] = match; sa[tid] = wrong ? 0.0 : 1.0;
    __syncthreads();
    for (int off = 128; off > 0; off >>= 1) {
        if (tid < off) {
            sl[tid] += sl[tid + off];
            sm_[tid] += sm_[tid + off];
            sa[tid] += sa[tid + off];
        }
        __syncthreads();
    }
    if (tid == 0) {
        out3[0] = (float)(sl[0] / (double)(T * B));
        out3[1] = (float)(sa[0] / (double)B);
        out3[2] = (float)(sm_[0] / (double)(T * B));
    }
}

// ===========================================================================
// Persistent cooperative kernel. Grid 512 = (jc 0..63) x (bc = bid&7).
// Thread: j_l = tid&7, b_l = tid>>3. All dataflow stays inside a bc-group
// (64 blocks) until the final full-grid barrier. LDS arena <= 30.5 KB.
// ===========================================================================
__global__ __launch_bounds__(NTHR, 2) void mono(
    const int* __restrict__ input_seq, const int* __restrict__ input_len,
    const int* __restrict__ target_seq,
    const float* __restrict__ enc_Whh, const float* __restrict__ enc_bhh,
    const float* __restrict__ att_W, const float* __restrict__ att_b,
    const float* __restrict__ dec_Wih, const float* __restrict__ dec_Whh,
    const float* __restrict__ dec_bih, const float* __restrict__ dec_bhh,
    const float* __restrict__ mlp_W, const float* __restrict__ out_W,
    const float* __restrict__ out_b,
    const float* __restrict__ gi_tab, const float* __restrict__ mlp_tab,
    float* __restrict__ h0, float* __restrict__ h1,
    float* __restrict__ ah, float* __restrict__ ctx, float* __restrict__ xbuf,
    float* __restrict__ logits, float* __restrict__ nll,
    float* __restrict__ enc_out, float* __restrict__ out,
    unsigned* __restrict__ bars)
{
    __shared__ __align__(16) char smem[ARENA_BYTES];
    float* Ht = (float*)(smem + HT_OFF);    // [32][68]
    float* Xt = (float*)(smem + XT_OFF);    // [32][68]
    float* Wa = (float*)(smem + WA_OFF);    // [24][68]
    float* Wb = (float*)(smem + WB_OFF);    // [24][68]

    const int bid = blockIdx.x, tid = threadIdx.x;
    const int bc = bid & 7, jc = bid >> 3;
    const int b0 = bc * 32, j0 = jc * 8;
    const int j_l = tid & 7, b_l = tid >> 3;
    const int b = b0 + b_l;
    const int j = j0 + j_l;
    unsigned gt = 0, ft = 0;
    unsigned* gbar = bars + bc * 32;
    unsigned* fbar = bars + 8 * 32;

    // ===== encoder scan =====
    {
        const double br = (double)enc_bhh[j], bz = (double)enc_bhh[512 + j],
                     bn = (double)enc_bhh[1024 + j];
        const int mylen = input_len[b];
        for (int s = 0; s < S; ++s) {
            const float* hcur = (s & 1) ? h1 : h0;
            float* hnxt = (s & 1) ? h0 : h1;
            double ar = 0.0, az = 0.0, an = 0.0;
            for (int kt = 0; kt < 512; kt += 64) {
                __syncthreads();
                for (int idx = tid; idx < 512 + 384; idx += NTHR) {
                    if (idx < 512) {
                        int row = idx >> 4, c4 = (idx & 15) * 4;
                        *(float4*)&Ht[row * 68 + c4] =
                            *(const float4*)(hcur + (size_t)(b0 + row) * 512 + kt + c4);
                    } else {
                        int w = idx - 512;
                        int row = w >> 4, c4 = (w & 15) * 4;
                        int g = row >> 3, jj = row & 7;
                        *(float4*)&Wa[row * 68 + c4] =
                            *(const float4*)(enc_Whh + (size_t)(g * 512 + j0 + jj) * 512 + kt + c4);
                    }
                }
                __syncthreads();
#pragma unroll
                for (int kk = 0; kk < 64; kk += 4) {
                    d4 hv = tod4(*(const float4*)&Ht[b_l * 68 + kk]);
                    ar += dotd(hv, tod4(*(const float4*)&Wa[j_l * 68 + kk]));
                    az += dotd(hv, tod4(*(const float4*)&Wa[(8 + j_l) * 68 + kk]));
                    an += dotd(hv, tod4(*(const float4*)&Wa[(16 + j_l) * 68 + kk]));
                }
            }
            float hold = hcur[(size_t)b * 512 + j];
            float hnew = hold;
            if (s < mylen) {
                int tok = input_seq[s * B + b];
                const float* gi = gi_tab + (size_t)tok * G3;
                double r = sigd((double)gi[j] + ar + br);
                double z = sigd((double)gi[512 + j] + az + bz);
                double n = tanh((double)gi[1024 + j] + r * (an + bn));
                hnew = (float)((1.0 - z) * n + z * (double)hold);
                enc_out[((size_t)s * B + b) * 512 + j] = hnew;
            }
            hnxt[(size_t)b * 512 + j] = hnew;
            gsync(gbar, &gt, 64);
        }
    }
    // h_enc in h0

    // P1 rows of stacked [att_W(512); out_W(512)]
    const int r1 = jc * 16 + j_l, r2 = r1 + 8;
    const bool p1_att = (jc < 32);

    // ===== decoder scan (t==T = logits/softmax epilogue) =====
    for (int t = 0; t <= T; ++t) {
        const float* hcur = (t & 1) ? h1 : h0;
        float* hnxt = (t & 1) ? h0 : h1;

        // ---- P1 ----
        {
            double a1 = 0.0, a2 = 0.0;
            for (int kt = 0; kt < 512; kt += 64) {
                __syncthreads();
                for (int idx = tid; idx < 512 + 256; idx += NTHR) {
                    if (idx < 512) {
                        int row = idx >> 4, c4 = (idx & 15) * 4;
                        *(float4*)&Ht[row * 68 + c4] =
                            *(const float4*)(hcur + (size_t)(b0 + row) * 512 + kt + c4);
                    } else {
                        int w = idx - 512;
                        int row = w >> 4, c4 = (w & 15) * 4;
                        int R = jc * 16 + row;
                        const float* src = (R < 512) ? (att_W + (size_t)R * 512)
                                                     : (out_W + (size_t)(R - 512) * 512);
                        *(float4*)&Wa[row * 68 + c4] = *(const float4*)(src + kt + c4);
                    }
                }
                __syncthreads();
#pragma unroll
                for (int kk = 0; kk < 64; kk += 4) {
                    d4 hv = tod4(*(const float4*)&Ht[b_l * 68 + kk]);
                    a1 += dotd(hv, tod4(*(const float4*)&Wa[j_l * 68 + kk]));
                    a2 += dotd(hv, tod4(*(const float4*)&Wa[(8 + j_l) * 68 + kk]));
                }
            }
            if (p1_att) {
                double v1 = a1 + (double)att_b[r1]; if (v1 < 0.0) v1 = 0.0;
                double v2 = a2 + (double)att_b[r2]; if (v2 < 0.0) v2 = 0.0;
                ah[(size_t)b * 512 + r1] = (float)v1;
                ah[(size_t)b * 512 + r2] = (float)v2;
            } else {
                logits[(size_t)b * 512 + (r1 - 512)] = (float)(a1 + (double)out_b[r1 - 512]);
                logits[(size_t)b * 512 + (r2 - 512)] = (float)(a2 + (double)out_b[r2 - 512]);
            }
        }
        gsync(gbar, &gt, 64);

        // ---- P2: attention (jc<32, t<T) | softmax for t-1 (jc>=32, t>=1) ----
        if (jc < 32) {
            if (t < T) {
                float* scx = (float*)(smem + SCX_OFF);
                double* sml = (double*)(smem + SML_OFF);
                const int ba = b0 + jc;
                const int wave = tid >> 6, lane = tid & 63;
                const int len = input_len[ba];
                const float* ahb = ah + (size_t)ba * 512;
                d4 aa1 = tod4(*(const float4*)(ahb + lane * 4));
                d4 aa2 = tod4(*(const float4*)(ahb + 256 + lane * 4));
                double m = -INFINITY, l = 0.0;
                d4 c1 = {0,0,0,0}, c2 = {0,0,0,0};
                for (int s = wave; s < len; s += 4) {
                    const float* row = enc_out + ((size_t)s * B + ba) * 512;
                    d4 e1 = tod4(*(const float4*)(row + lane * 4));
                    d4 e2 = tod4(*(const float4*)(row + 256 + lane * 4));
                    double p = dotd(e1, aa1) + dotd(e2, aa2);
#pragma unroll
                    for (int off = 32; off >= 1; off >>= 1) p += __shfl_xor(p, off, 64);
                    double mn = fmax(m, p);
                    double sc = exp(m - mn), w = exp(p - mn);
                    l = l * sc + w;
                    c1.x = c1.x * sc + w * e1.x; c1.y = c1.y * sc + w * e1.y;
                    c1.z = c1.z * sc + w * e1.z; c1.w = c1.w * sc + w * e1.w;
                    c2.x = c2.x * sc + w * e2.x; c2.y = c2.y * sc + w * e2.y;
                    c2.z = c2.z * sc + w * e2.z; c2.w = c2.w * sc + w * e2.w;
                    m = mn;
                }
                if (lane == 0) { sml[wave] = m; sml[4 + wave] = l; }
                *(float4*)&scx[wave * 512 + lane * 4] =
                    make_float4((float)c1.x, (float)c1.y, (float)c1.z, (float)c1.w);
                *(float4*)&scx[wave * 512 + 256 + lane * 4] =
                    make_float4((float)c2.x, (float)c2.y, (float)c2.z, (float)c2.w);
                __syncthreads();
                double M = fmax(fmax(sml[0], sml[1]), fmax(sml[2], sml[3]));
                if (len < S) M = fmax(M, 0.0);
                double w0 = exp(sml[0] - M), w1x = exp(sml[1] - M);
                double w2x = exp(sml[2] - M), w3 = exp(sml[3] - M);
                double L = sml[4] * w0 + sml[5] * w1x + sml[6] * w2x + sml[7] * w3
                         + (double)(S - len) * exp(0.0 - M);
                for (int jj = tid; jj < 512; jj += NTHR) {
                    double v = (double)scx[0 * 512 + jj] * w0 + (double)scx[1 * 512 + jj] * w1x
                             + (double)scx[2 * 512 + jj] * w2x + (double)scx[3 * 512 + jj] * w3;
                    ctx[(size_t)ba * 512 + jj] = (float)(v / L);
                }
                __syncthreads();
            }
        } else {
            if (t >= 1) {
                float* red_f = (float*)(smem + REDF_OFF);
                double* red_d = (double*)(smem + REDD_OFF);
                int* red_i = (int*)(smem + REDI_OFF);
                const int sb = b0 + (jc - 32);
                const float* lg = logits + (size_t)sb * 512;
                const float l0 = lg[tid], l1 = lg[256 + tid];
                red_f[tid] = fmaxf(l0, l1);
                __syncthreads();
                for (int off = 128; off > 0; off >>= 1) {
                    if (tid < off) red_f[tid] = fmaxf(red_f[tid], red_f[tid + off]);
                    __syncthreads();
                }
                const double mx = (double)red_f[0];
                __syncthreads();
                const double e0 = exp((double)l0 - mx), e1 = exp((double)l1 - mx);
                red_d[tid] = e0 + e1;
                __syncthreads();
                for (int off = 128; off > 0; off >>= 1) {
                    if (tid < off) red_d[tid] += red_d[tid + off];
                    __syncthreads();
                }
                const double Z = red_d[0];
                __syncthreads();
                const float p0 = (float)(e0 / Z), p1 = (float)(e1 / Z);
                float v; int idx;
                if (p0 >= p1) { v = p0; idx = tid; } else { v = p1; idx = 256 + tid; }
                red_f[tid] = v; red_i[tid] = idx;
                __syncthreads();
                for (int off = 128; off > 0; off >>= 1) {
                    if (tid < off) {
                        float ov = red_f[tid + off]; int oi = red_i[tid + off];
                        if (ov > red_f[tid] || (ov == red_f[tid] && oi < red_i[tid])) {
                            red_f[tid] = ov; red_i[tid] = oi;
                        }
                    }
                    __syncthreads();
                }
                if (tid == 0) {
                    int tg = target_seq[(t - 1) * B + sb];
                    float pt = (float)(exp((double)lg[tg] - mx) / Z);
                    pt = fmaxf(pt, 1e-10f);
                    nll[(t - 1) * B + sb] = (float)(-log((double)pt));
                    out[(t - 1) * B + sb] = (float)red_i[0];
                }
                __syncthreads();
            }
        }
        gsync(gbar, &gt, 64);

        if (t < T) {
            // ---- P2b: x = tanh(mlp_tab[tok] + ctx @ mlpW[:,512:].T) ----
            {
                double a = 0.0;
                for (int kt = 0; kt < 512; kt += 64) {
                    __syncthreads();
                    for (int idx = tid; idx < 512 + 128; idx += NTHR) {
                        if (idx < 512) {
                            int row = idx >> 4, c4 = (idx & 15) * 4;
                            *(float4*)&Ht[row * 68 + c4] =
                                *(const float4*)(ctx + (size_t)(b0 + row) * 512 + kt + c4);
                        } else {
                            int w = idx - 512;
                            int row = w >> 4, c4 = (w & 15) * 4;
                            *(float4*)&Wa[row * 68 + c4] =
                                *(const float4*)(mlp_W + (size_t)(j0 + row) * 1024 + 512 + kt + c4);
                        }
                    }
                    __syncthreads();
#pragma unroll
                    for (int kk = 0; kk < 64; kk += 4) {
                        a += dotd(tod4(*(const float4*)&Ht[b_l * 68 + kk]),
                                  tod4(*(const float4*)&Wa[j_l * 68 + kk]));
                    }
                }
                const int tok = (t == 0) ? 1 : target_seq[(t - 1) * B + b];
                xbuf[(size_t)b * 512 + j] =
                    (float)tanh((double)mlp_tab[(size_t)tok * 512 + j] + a);
            }
            gsync(gbar, &gt, 64);

            // ---- P3: GRU ----
            {
                double air = 0, aiz = 0, ain = 0, ahr = 0, ahz = 0, ahn = 0;
                for (int kt = 0; kt < 512; kt += 64) {
                    __syncthreads();
                    for (int idx = tid; idx < 1792; idx += NTHR) {
                        if (idx < 512) {
                            int row = idx >> 4, c4 = (idx & 15) * 4;
                            *(float4*)&Ht[row * 68 + c4] =
                                *(const float4*)(hcur + (size_t)(b0 + row) * 512 + kt + c4);
                        } else if (idx < 1024) {
                            int w = idx - 512;
                            int row = w >> 4, c4 = (w & 15) * 4;
                            *(float4*)&Xt[row * 68 + c4] =
                                *(const float4*)(xbuf + (size_t)(b0 + row) * 512 + kt + c4);
                        } else if (idx < 1408) {
                            int w = idx - 1024;
                            int row = w >> 4, c4 = (w & 15) * 4;
                            int g = row >> 3, jj = row & 7;
                            *(float4*)&Wa[row * 68 + c4] =
                                *(const float4*)(dec_Wih + (size_t)(g * 512 + j0 + jj) * 512 + kt + c4);
                        } else {
                            int w = idx - 1408;
                            int row = w >> 4, c4 = (w & 15) * 4;
                            int g = row >> 3, jj = row & 7;
                            *(float4*)&Wb[row * 68 + c4] =
                                *(const float4*)(dec_Whh + (size_t)(g * 512 + j0 + jj) * 512 + kt + c4);
                        }
                    }
                    __syncthreads();
#pragma unroll
                    for (int kk = 0; kk < 64; kk += 4) {
                        d4 xv = tod4(*(const float4*)&Xt[b_l * 68 + kk]);
                        d4 hv = tod4(*(const float4*)&Ht[b_l * 68 + kk]);
                        air += dotd(xv, tod4(*(const float4*)&Wa[j_l * 68 + kk]));
                        aiz += dotd(xv, tod4(*(const float4*)&Wa[(8 + j_l) * 68 + kk]));
                        ain += dotd(xv, tod4(*(const float4*)&Wa[(16 + j_l) * 68 + kk]));
                        ahr += dotd(hv, tod4(*(const float4*)&Wb[j_l * 68 + kk]));
                        ahz += dotd(hv, tod4(*(const float4*)&Wb[(8 + j_l) * 68 + kk]));
                        ahn += dotd(hv, tod4(*(const float4*)&Wb[(16 + j_l) * 68 + kk]));
                    }
                }
                double r = sigd(air + (double)dec_bih[j] + ahr + (double)dec_bhh[j]);
                double z = sigd(aiz + (double)dec_bih[512 + j] + ahz + (double)dec_bhh[512 + j]);
                double n = tanh(ain + (double)dec_bih[1024 + j]
                                + r * (ahn + (double)dec_bhh[1024 + j]));
                float hold = hcur[(size_t)b * 512 + j];
                hnxt[(size_t)b * 512 + j] = (float)((1.0 - z) * n + z * (double)hold);
            }
            gsync(gbar, &gt, 64);
        }
    }

    // ===== full-grid barrier, finalize in block 0 =====
    gsync(fbar, &ft, NBLK);
    if (bid == 0) {
        double* red_d = (double*)(smem + REDD_OFF);
        int wrong = 0; double match = 0.0;
        for (int tt = 0; tt < T; ++tt) {
            float inf = out[tt * B + tid];
            float tg = (float)target_seq[tt * B + tid];
            bool ok = (inf == tg);
            match += ok ? 1.0 : 0.0;
            wrong |= !ok;
        }
        double lsum = 0.0;
        for (int i = tid; i < T * B; i += NTHR) lsum += (double)nll[i];
        red_d[tid] = lsum; __syncthreads();
        for (int off = 128; off > 0; off >>= 1) {
            if (tid < off) red_d[tid] += red_d[tid + off];
            __syncthreads();
        }
        double Lsum = red_d[0]; __syncthreads();
        red_d[tid] = match; __syncthreads();
        for (int off = 128; off > 0; off >>= 1) {
            if (tid < off) red_d[tid] += red_d[tid + off];
            __syncthreads();
        }
        double Msum = red_d[0]; __syncthreads();
        red_d[tid] = wrong ? 0.0 : 1.0; __syncthreads();
        for (int off = 128; off > 0; off >>= 1) {
            if (tid < off) red_d[tid] += red_d[tid + off];
            __syncthreads();
        }
        if (tid == 0) {
            float* o3 = out + (size_t)T * B;
            o3[0] = (float)(Lsum / (double)(T * B));
            o3[1] = (float)(red_d[0] / (double)B);
            o3[2] = (float)(Msum / (double)(T * B));
        }
    }
}

// ---------------------------------------------------------------------------
extern "C" void kernel_launch(void* const* d_in, const int* in_sizes, int n_in,
                              void* d_out, int out_size, void* d_ws, size_t ws_size,
                              hipStream_t stream)
{
    const int*   input_seq  = (const int*)d_in[0];
    const int*   input_len  = (const int*)d_in[1];
    const int*   target_seq = (const int*)d_in[2];
    const float* enc_embed  = (const float*)d_in[3];
    const float* enc_Wih    = (const float*)d_in[4];
    const float* enc_Whh    = (const float*)d_in[5];
    const float* enc_bih    = (const float*)d_in[6];
    const float* enc_bhh    = (const float*)d_in[7];
    const float* att_W      = (const float*)d_in[8];
    const float* att_b      = (const float*)d_in[9];
    const float* dec_embed  = (const float*)d_in[10];
    const float* dec_Wih    = (const float*)d_in[11];
    const float* dec_Whh    = (const float*)d_in[12];
    const float* dec_bih    = (const float*)d_in[13];
    const float* dec_bhh    = (const float*)d_in[14];
    const float* mlp_W      = (const float*)d_in[15];
    const float* mlp_b      = (const float*)d_in[16];
    const float* out_W      = (const float*)d_in[17];
    const float* out_b      = (const float*)d_in[18];

    float* out = (float*)d_out;   // [inference (T*B) | loss | acc | all_acc]

    float* gi_tab  = (float*)d_ws;                   // (V, 3H)
    float* mlp_tab = gi_tab + (size_t)VOC * G3;      // (V, H)
    float* h0      = mlp_tab + (size_t)VOC * Hh;     // (B, H)
    float* h1      = h0 + (size_t)B * Hh;
    float* ahb     = h1 + (size_t)B * Hh;
    float* ctxb    = ahb + (size_t)B * Hh;
    float* xb      = ctxb + (size_t)B * Hh;
    float* lgb     = xb + (size_t)B * Hh;
    float* nllb    = lgb + (size_t)B * Hh;           // (T, B)
    float* barsf   = nllb + (size_t)T * B;           // 512 u32 barrier counters
    float* enc_out = barsf + 512;                    // (S, B, H) ~100 MB
    unsigned* bars = (unsigned*)barsf;

    hipMemsetAsync(h0, 0, (size_t)B * Hh * sizeof(float), stream);
    hipMemsetAsync(bars, 0, 512 * sizeof(unsigned), stream);

    // Precompute tables
    gemm_at<<<dim3(48, 16), 256, 0, stream>>>(
        enc_embed, enc_Wih, 512, 0, enc_bih, nullptr, nullptr, 0, gi_tab, G3, 0);
    gemm_at<<<dim3(16, 16), 256, 0, stream>>>(
        dec_embed, mlp_W, 1024, 0, mlp_b, nullptr, nullptr, 0, mlp_tab, Hh, 0);

    void* args[] = {
        (void*)&input_seq, (void*)&input_len, (void*)&target_seq,
        (void*)&enc_Whh, (void*)&enc_bhh,
        (void*)&att_W, (void*)&att_b,
        (void*)&dec_Wih, (void*)&dec_Whh, (void*)&dec_bih, (void*)&dec_bhh,
        (void*)&mlp_W, (void*)&out_W, (void*)&out_b,
        (void*)&gi_tab, (void*)&mlp_tab,
        (void*)&h0, (void*)&h1, (void*)&ahb, (void*)&ctxb, (void*)&xb,
        (void*)&lgb, (void*)&nllb, (void*)&enc_out, (void*)&out,
        (void*)&bars
    };
    hipError_t e = hipLaunchCooperativeKernel((const void*)mono, dim3(NBLK), dim3(NTHR),
                                              args, 0, stream);
    if (e != hipSuccess) {
        // Deterministic fallback: the proven round-2 multi-launch path.
        (void)hipGetLastError();  // clear error state
        for (int s = 0; s < S; ++s) {
            const float* hc = (s & 1) ? h1 : h0;
            float* hx = (s & 1) ? h0 : h1;
            enc_step<<<dim3(32, 8), 256, 0, stream>>>(
                hc, hx, gi_tab, input_seq, input_len, enc_Whh, enc_bhh, s, enc_out);
        }
        for (int t = 0; t < T; ++t) {
            const float* hc = (t & 1) ? h1 : h0;
            float* hx = (t & 1) ? h0 : h1;
            gemm_at<<<dim3(16, 8), 256, 0, stream>>>(
                hc, att_W, 512, 0, att_b, nullptr, nullptr, 0, ahb, Hh, 1);
            attn_step<<<dim3(B), 256, 0, stream>>>(enc_out, ahb, ctxb);
            gemm_at<<<dim3(16, 8), 256, 0, stream>>>(
                ctxb, mlp_W, 1024, 512, nullptr, mlp_tab, target_seq, t, xb, Hh, 2);
            dec_gru<<<dim3(32, 8), 256, 0, stream>>>(
                xb, hc, dec_Wih, dec_Whh, dec_bih, dec_bhh, hx);
            gemm_at<<<dim3(16, 8), 256, 0, stream>>>(
                hx, out_W, 512, 0, out_b, nullptr, nullptr, 0, lgb, Hh, 0);
            softmax_loss<<<dim3(B), 256, 0, stream>>>(lgb, target_seq, t, nllb, out);
        }
        finalize_k<<<dim3(1), 256, 0, stream>>>(nllb, out, target_seq, out + (size_t)T * B);
    }
}

// Round 5
// 44821.881 us; speedup vs baseline: 3.2478x; 3.2478x over previous
//
#include <hip/hip_runtime.h>
#include <math.h>

// Problem constants
#define B 256
#define Hh 512
#define S 200
#define T 200
#define VOC 512
#define G3 1536
#define PAD 36

// fp64 helpers: inner-product math in double, tensor boundaries quantized fp32.
struct d4 { double x, y, z, w; };
__device__ __forceinline__ d4 tod4(const float4 a) {
    d4 r; r.x = a.x; r.y = a.y; r.z = a.z; r.w = a.w; return r;
}
__device__ __forceinline__ double dotd(const d4& a, const d4& b) {
    return a.x * b.x + a.y * b.y + a.z * b.z + a.w * b.w;
}
__device__ __forceinline__ double sigd(double x) { return 1.0 / (1.0 + exp(-x)); }

// ---------------------------------------------------------------------------
// Table-precompute GEMM (round-2 proven): C[m,j] = act(sum_k A[m,k]*W[j*ldw+woff+k]
//                                          + bias[j]). act: 0 none.
// ---------------------------------------------------------------------------
__global__ __launch_bounds__(256) void gemm_at(
    const float* __restrict__ A,
    const float* __restrict__ W, int ldw, int woff,
    const float* __restrict__ bias,
    float* __restrict__ C, int ldc)
{
    __shared__ float As[32][PAD];
    __shared__ float Ws[32][PAD];
    const int tid = threadIdx.x;
    const int tx = tid & 15, ty = tid >> 4;
    const int j0 = blockIdx.x * 32, m0 = blockIdx.y * 32;
    const int lr = tid >> 3, lc = (tid & 7) * 4;

    double acc00 = 0.0, acc01 = 0.0, acc10 = 0.0, acc11 = 0.0;

    for (int k0 = 0; k0 < 512; k0 += 32) {
        float4 av = *(const float4*)(A + (size_t)(m0 + lr) * 512 + k0 + lc);
        float4 wv = *(const float4*)(W + (size_t)(j0 + lr) * ldw + woff + k0 + lc);
        __syncthreads();
        *(float4*)&As[lr][lc] = av;
        *(float4*)&Ws[lr][lc] = wv;
        __syncthreads();
#pragma unroll
        for (int kk = 0; kk < 32; kk += 4) {
            d4 a0 = tod4(*(const float4*)&As[ty][kk]);
            d4 a1 = tod4(*(const float4*)&As[ty + 16][kk]);
            d4 b0 = tod4(*(const float4*)&Ws[tx][kk]);
            d4 b1 = tod4(*(const float4*)&Ws[tx + 16][kk]);
            acc00 += dotd(a0, b0);
            acc01 += dotd(a0, b1);
            acc10 += dotd(a1, b0);
            acc11 += dotd(a1, b1);
        }
    }
    const int ms[2] = { m0 + ty, m0 + ty + 16 };
    const int js[2] = { j0 + tx, j0 + tx + 16 };
    double accs[2][2] = { { acc00, acc01 }, { acc10, acc11 } };
#pragma unroll
    for (int mi = 0; mi < 2; ++mi)
#pragma unroll
        for (int ji = 0; ji < 2; ++ji) {
            int m = ms[mi], j = js[ji];
            C[(size_t)m * ldc + j] = (float)(accs[mi][ji] + (double)bias[j]);
        }
}

// ---------------------------------------------------------------------------
// Encoder GRU step (round-2 proven + early-out for fully-masked b-tiles).
// Grid (32, 8): j0 = bx*16, b0 = by*32.
// ---------------------------------------------------------------------------
__global__ __launch_bounds__(256) void enc_step(
    const float* __restrict__ h_in, float* __restrict__ h_out,
    const float* __restrict__ gi_tab, const int* __restrict__ iseq,
    const int* __restrict__ ilen, const float* __restrict__ Whh,
    const float* __restrict__ bhh, int s, float* __restrict__ enc_out)
{
    __shared__ float Hs[32][PAD];
    __shared__ float Ws[48][PAD];
    const int tid = threadIdx.x;
    const int tx = tid & 15, ty = tid >> 4;
    const int j0 = blockIdx.x * 16, b0 = blockIdx.y * 32;
    const int lr = tid >> 3, lc = (tid & 7) * 4;

    // Early-out: if every batch in this tile is past its length, the step is
    // a pure copy (h unchanged) + zero enc_out rows — skip the GEMM.
    int ml = 0;
    for (int i = 0; i < 32; ++i) ml = max(ml, ilen[b0 + i]);
    if (s >= ml) {
        const int j = j0 + tx;
#pragma unroll
        for (int bb = 0; bb < 2; ++bb) {
            int b = b0 + ty + 16 * bb;
            h_out[(size_t)b * 512 + j] = h_in[(size_t)b * 512 + j];
            enc_out[((size_t)s * B + b) * 512 + j] = 0.f;
        }
        return;
    }

    double ar0 = 0.0, az0 = 0.0, an0 = 0.0;
    double ar1 = 0.0, az1 = 0.0, an1 = 0.0;

    for (int k0 = 0; k0 < 512; k0 += 32) {
        float4 hv = *(const float4*)(h_in + (size_t)(b0 + lr) * 512 + k0 + lc);
        int g0 = lr >> 4, jj0 = lr & 15;
        float4 wv0 = *(const float4*)(Whh + (size_t)(g0 * 512 + j0 + jj0) * 512 + k0 + lc);
        float4 wv1;
        if (tid < 128) {
            int jj1 = lr & 15;
            wv1 = *(const float4*)(Whh + (size_t)(2 * 512 + j0 + jj1) * 512 + k0 + lc);
        }
        __syncthreads();
        *(float4*)&Hs[lr][lc] = hv;
        *(float4*)&Ws[lr][lc] = wv0;
        if (tid < 128) *(float4*)&Ws[32 + lr][lc] = wv1;
        __syncthreads();
#pragma unroll
        for (int kk = 0; kk < 32; kk += 4) {
            d4 a0 = tod4(*(const float4*)&Hs[ty][kk]);
            d4 a1 = tod4(*(const float4*)&Hs[ty + 16][kk]);
            d4 wr = tod4(*(const float4*)&Ws[tx][kk]);
            d4 wz = tod4(*(const float4*)&Ws[16 + tx][kk]);
            d4 wn = tod4(*(const float4*)&Ws[32 + tx][kk]);
            ar0 += dotd(a0, wr); az0 += dotd(a0, wz); an0 += dotd(a0, wn);
            ar1 += dotd(a1, wr); az1 += dotd(a1, wz); an1 += dotd(a1, wn);
        }
    }
    const int j = j0 + tx;
    const double br = (double)bhh[j], bz = (double)bhh[512 + j], bn = (double)bhh[1024 + j];
    double gr[2] = { ar0, ar1 }, gz[2] = { az0, az1 }, gn[2] = { an0, an1 };
#pragma unroll
    for (int bb = 0; bb < 2; ++bb) {
        int b = b0 + ty + 16 * bb;
        int tok = iseq[s * B + b];
        const float* gi = gi_tab + (size_t)tok * G3;
        double r = sigd((double)gi[j] + gr[bb] + br);
        double z = sigd((double)gi[512 + j] + gz[bb] + bz);
        double n = tanh((double)gi[1024 + j] + r * (gn[bb] + bn));
        float hold = h_in[(size_t)b * 512 + j];
        float hn = (float)((1.0 - z) * n + z * (double)hold);
        bool msk = s < ilen[b];
        float hnew = msk ? hn : hold;
        h_out[(size_t)b * 512 + j] = hnew;
        enc_out[((size_t)s * B + b) * 512 + j] = msk ? hnew : 0.f;
    }
}

// ---------------------------------------------------------------------------
// K_a: dual GEMM over stacked rows [att_W (0..511); out_W (512..1023)]:
//   R < 512:  ah[m,R]       = relu(h@attW.T + att_b)
//   R >= 512: logits[m,R-512] = h@outW.T + out_b
// Grid (32, 8): j0 = bx*32 (tile never straddles the 512 boundary).
// ---------------------------------------------------------------------------
__global__ __launch_bounds__(256) void gemm_dual(
    const float* __restrict__ h,
    const float* __restrict__ att_W, const float* __restrict__ att_b,
    const float* __restrict__ out_W, const float* __restrict__ out_b,
    float* __restrict__ ah, float* __restrict__ logits)
{
    __shared__ float As[32][PAD];
    __shared__ float Ws[32][PAD];
    const int tid = threadIdx.x;
    const int tx = tid & 15, ty = tid >> 4;
    const int j0 = blockIdx.x * 32, m0 = blockIdx.y * 32;
    const int lr = tid >> 3, lc = (tid & 7) * 4;
    const bool is_att = (j0 < 512);

    double acc00 = 0.0, acc01 = 0.0, acc10 = 0.0, acc11 = 0.0;

    for (int k0 = 0; k0 < 512; k0 += 32) {
        float4 av = *(const float4*)(h + (size_t)(m0 + lr) * 512 + k0 + lc);
        int R = j0 + lr;
        const float* wsrc = is_att ? (att_W + (size_t)R * 512)
                                   : (out_W + (size_t)(R - 512) * 512);
        float4 wv = *(const float4*)(wsrc + k0 + lc);
        __syncthreads();
        *(float4*)&As[lr][lc] = av;
        *(float4*)&Ws[lr][lc] = wv;
        __syncthreads();
#pragma unroll
        for (int kk = 0; kk < 32; kk += 4) {
            d4 a0 = tod4(*(const float4*)&As[ty][kk]);
            d4 a1 = tod4(*(const float4*)&As[ty + 16][kk]);
            d4 b0 = tod4(*(const float4*)&Ws[tx][kk]);
            d4 b1 = tod4(*(const float4*)&Ws[tx + 16][kk]);
            acc00 += dotd(a0, b0);
            acc01 += dotd(a0, b1);
            acc10 += dotd(a1, b0);
            acc11 += dotd(a1, b1);
        }
    }
    const int ms[2] = { m0 + ty, m0 + ty + 16 };
    const int js[2] = { j0 + tx, j0 + tx + 16 };
    double accs[2][2] = { { acc00, acc01 }, { acc10, acc11 } };
#pragma unroll
    for (int mi = 0; mi < 2; ++mi)
#pragma unroll
        for (int ji = 0; ji < 2; ++ji) {
            int m = ms[mi], R = js[ji];
            double v = accs[mi][ji];
            if (is_att) {
                v += (double)att_b[R];
                if (v < 0.0) v = 0.0;
                ah[(size_t)m * 512 + R] = (float)v;
            } else {
                v += (double)out_b[R - 512];
                logits[(size_t)m * 512 + (R - 512)] = (float)v;
            }
        }
}

// ---------------------------------------------------------------------------
// K_b: blocks 0..255  -> attention (truncated, analytic zero tail) + in-block
//                        x = tanh(mlp_tab[tok] + ctx @ mlpW2.T)   [skip t==T]
//      blocks 256..511-> softmax/argmax/nll for step t-1           [skip t==0]
// ---------------------------------------------------------------------------
__global__ __launch_bounds__(256) void attn_x_softmax(
    const float* __restrict__ enc_out, const float* __restrict__ ah,
    const float* __restrict__ mlp_W, const float* __restrict__ mlp_tab,
    const int* __restrict__ input_len, const int* __restrict__ target_seq,
    const float* __restrict__ logits, int t,
    float* __restrict__ xbuf, float* __restrict__ nll,
    float* __restrict__ inference)
{
    const int bid = blockIdx.x, tid = threadIdx.x;

    if (bid < B) {
        if (t >= T) return;
        // ---------------- attention + x for batch b ----------------
        __shared__ float scx[4][512];
        __shared__ double sml[8];
        __shared__ float ctxl[512];
        const int b = bid;
        const int wave = tid >> 6, lane = tid & 63;
        const int len = input_len[b];
        const float* ahb = ah + (size_t)b * 512;
        d4 aa1 = tod4(*(const float4*)(ahb + lane * 4));
        d4 aa2 = tod4(*(const float4*)(ahb + 256 + lane * 4));
        double m = -INFINITY, l = 0.0;
        d4 c1 = {0,0,0,0}, c2 = {0,0,0,0};
        for (int s = wave; s < len; s += 4) {
            const float* row = enc_out + ((size_t)s * B + b) * 512;
            d4 e1 = tod4(*(const float4*)(row + lane * 4));
            d4 e2 = tod4(*(const float4*)(row + 256 + lane * 4));
            double p = dotd(e1, aa1) + dotd(e2, aa2);
#pragma unroll
            for (int off = 32; off >= 1; off >>= 1) p += __shfl_xor(p, off, 64);
            double mn = fmax(m, p);
            double sc = exp(m - mn), w = exp(p - mn);
            l = l * sc + w;
            c1.x = c1.x * sc + w * e1.x; c1.y = c1.y * sc + w * e1.y;
            c1.z = c1.z * sc + w * e1.z; c1.w = c1.w * sc + w * e1.w;
            c2.x = c2.x * sc + w * e2.x; c2.y = c2.y * sc + w * e2.y;
            c2.z = c2.z * sc + w * e2.z; c2.w = c2.w * sc + w * e2.w;
            m = mn;
        }
        if (lane == 0) { sml[wave] = m; sml[4 + wave] = l; }
        *(float4*)&scx[wave][lane * 4] =
            make_float4((float)c1.x, (float)c1.y, (float)c1.z, (float)c1.w);
        *(float4*)&scx[wave][256 + lane * 4] =
            make_float4((float)c2.x, (float)c2.y, (float)c2.z, (float)c2.w);
        __syncthreads();
        double M = fmax(fmax(sml[0], sml[1]), fmax(sml[2], sml[3]));
        if (len < S) M = fmax(M, 0.0);   // zero rows participate in softmax
        double w0 = exp(sml[0] - M), w1x = exp(sml[1] - M);
        double w2x = exp(sml[2] - M), w3 = exp(sml[3] - M);
        double L = sml[4] * w0 + sml[5] * w1x + sml[6] * w2x + sml[7] * w3
                 + (double)(S - len) * exp(0.0 - M);   // analytic zero tail
        for (int jj = tid; jj < 512; jj += 256) {
            double v = (double)scx[0][jj] * w0 + (double)scx[1][jj] * w1x
                     + (double)scx[2][jj] * w2x + (double)scx[3][jj] * w3;
            ctxl[jj] = (float)(v / L);   // fp32 quantization boundary (as ref)
        }
        __syncthreads();

        // x phase: rows striped over waves, lanes split k (coalesced W2 reads)
        const int tok = (t == 0) ? 1 : target_seq[(t - 1) * B + b];
        d4 cv1 = tod4(*(const float4*)&ctxl[lane * 8]);
        d4 cv2 = tod4(*(const float4*)&ctxl[lane * 8 + 4]);
        for (int jr = wave; jr < 512; jr += 4) {
            const float* wr = mlp_W + (size_t)jr * 1024 + 512;
            d4 wv1 = tod4(*(const float4*)(wr + lane * 8));
            d4 wv2 = tod4(*(const float4*)(wr + lane * 8 + 4));
            double p = dotd(wv1, cv1) + dotd(wv2, cv2);
#pragma unroll
            for (int off = 32; off >= 1; off >>= 1) p += __shfl_xor(p, off, 64);
            if (lane == 0)
                xbuf[(size_t)b * 512 + jr] =
                    (float)tanh((double)mlp_tab[(size_t)tok * 512 + jr] + p);
        }
    } else {
        if (t < 1) return;
        // ---------------- softmax / argmax / nll for (t-1, b) ----------------
        __shared__ float red_f[256];
        __shared__ double red_d[256];
        __shared__ int red_i[256];
        const int sb = bid - B;
        const float* lg = logits + (size_t)sb * 512;
        const float l0 = lg[tid], l1 = lg[256 + tid];
        red_f[tid] = fmaxf(l0, l1);
        __syncthreads();
        for (int off = 128; off > 0; off >>= 1) {
            if (tid < off) red_f[tid] = fmaxf(red_f[tid], red_f[tid + off]);
            __syncthreads();
        }
        const double mx = (double)red_f[0];
        __syncthreads();
        const double e0 = exp((double)l0 - mx), e1 = exp((double)l1 - mx);
        red_d[tid] = e0 + e1;
        __syncthreads();
        for (int off = 128; off > 0; off >>= 1) {
            if (tid < off) red_d[tid] += red_d[tid + off];
            __syncthreads();
        }
        const double Z = red_d[0];
        __syncthreads();
        const float p0 = (float)(e0 / Z), p1 = (float)(e1 / Z);
        float v; int idx;
        if (p0 >= p1) { v = p0; idx = tid; } else { v = p1; idx = 256 + tid; }
        red_f[tid] = v; red_i[tid] = idx;
        __syncthreads();
        for (int off = 128; off > 0; off >>= 1) {
            if (tid < off) {
                float ov = red_f[tid + off]; int oi = red_i[tid + off];
                if (ov > red_f[tid] || (ov == red_f[tid] && oi < red_i[tid])) {
                    red_f[tid] = ov; red_i[tid] = oi;
                }
            }
            __syncthreads();
        }
        if (tid == 0) {
            int tg = target_seq[(t - 1) * B + sb];
            float pt = (float)(exp((double)lg[tg] - mx) / Z);
            pt = fmaxf(pt, 1e-10f);
            nll[(t - 1) * B + sb] = (float)(-log((double)pt));
            inference[(t - 1) * B + sb] = (float)red_i[0];
        }
    }
}

// ---------------------------------------------------------------------------
// K_d: decoder GRU (round-2 proven). Grid (32, 8).
// ---------------------------------------------------------------------------
__global__ __launch_bounds__(256) void dec_gru(
    const float* __restrict__ x, const float* __restrict__ h_in,
    const float* __restrict__ Wih, const float* __restrict__ Whh,
    const float* __restrict__ bih, const float* __restrict__ bhh,
    float* __restrict__ h_out)
{
    __shared__ float Xs[32][PAD];
    __shared__ float Hs[32][PAD];
    __shared__ float Wi[48][PAD];
    __shared__ float Wh[48][PAD];
    const int tid = threadIdx.x;
    const int tx = tid & 15, ty = tid >> 4;
    const int j0 = blockIdx.x * 16, b0 = blockIdx.y * 32;
    const int lr = tid >> 3, lc = (tid & 7) * 4;

    double air0 = 0, aiz0 = 0, ain0 = 0, ahr0 = 0, ahz0 = 0, ahn0 = 0;
    double air1 = 0, aiz1 = 0, ain1 = 0, ahr1 = 0, ahz1 = 0, ahn1 = 0;

    for (int k0 = 0; k0 < 512; k0 += 32) {
        float4 xv = *(const float4*)(x + (size_t)(b0 + lr) * 512 + k0 + lc);
        float4 hv = *(const float4*)(h_in + (size_t)(b0 + lr) * 512 + k0 + lc);
        int g0 = lr >> 4, jj0 = lr & 15;
        float4 wi0 = *(const float4*)(Wih + (size_t)(g0 * 512 + j0 + jj0) * 512 + k0 + lc);
        float4 wh0 = *(const float4*)(Whh + (size_t)(g0 * 512 + j0 + jj0) * 512 + k0 + lc);
        float4 wi1, wh1;
        if (tid < 128) {
            int jj1 = lr & 15;
            wi1 = *(const float4*)(Wih + (size_t)(2 * 512 + j0 + jj1) * 512 + k0 + lc);
            wh1 = *(const float4*)(Whh + (size_t)(2 * 512 + j0 + jj1) * 512 + k0 + lc);
        }
        __syncthreads();
        *(float4*)&Xs[lr][lc] = xv;
        *(float4*)&Hs[lr][lc] = hv;
        *(float4*)&Wi[lr][lc] = wi0;
        *(float4*)&Wh[lr][lc] = wh0;
        if (tid < 128) { *(float4*)&Wi[32 + lr][lc] = wi1; *(float4*)&Wh[32 + lr][lc] = wh1; }
        __syncthreads();
#pragma unroll
        for (int kk = 0; kk < 32; kk += 4) {
            d4 x0 = tod4(*(const float4*)&Xs[ty][kk]);
            d4 x1 = tod4(*(const float4*)&Xs[ty + 16][kk]);
            d4 h0 = tod4(*(const float4*)&Hs[ty][kk]);
            d4 h1 = tod4(*(const float4*)&Hs[ty + 16][kk]);
            d4 wir = tod4(*(const float4*)&Wi[tx][kk]);
            d4 wiz = tod4(*(const float4*)&Wi[16 + tx][kk]);
            d4 win = tod4(*(const float4*)&Wi[32 + tx][kk]);
            d4 whr = tod4(*(const float4*)&Wh[tx][kk]);
            d4 whz = tod4(*(const float4*)&Wh[16 + tx][kk]);
            d4 whn = tod4(*(const float4*)&Wh[32 + tx][kk]);
            air0 += dotd(x0, wir); aiz0 += dotd(x0, wiz); ain0 += dotd(x0, win);
            ahr0 += dotd(h0, whr); ahz0 += dotd(h0, whz); ahn0 += dotd(h0, whn);
            air1 += dotd(x1, wir); aiz1 += dotd(x1, wiz); ain1 += dotd(x1, win);
            ahr1 += dotd(h1, whr); ahz1 += dotd(h1, whz); ahn1 += dotd(h1, whn);
        }
    }
    const int j = j0 + tx;
    const double bir = (double)bih[j], biz = (double)bih[512 + j], bin = (double)bih[1024 + j];
    const double bhr = (double)bhh[j], bhz = (double)bhh[512 + j], bhn = (double)bhh[1024 + j];
    double ir[2] = { air0, air1 }, iz[2] = { aiz0, aiz1 }, in_[2] = { ain0, ain1 };
    double hr[2] = { ahr0, ahr1 }, hz[2] = { ahz0, ahz1 }, hn_[2] = { ahn0, ahn1 };
#pragma unroll
    for (int bb = 0; bb < 2; ++bb) {
        int b = b0 + ty + 16 * bb;
        double r = sigd(ir[bb] + bir + hr[bb] + bhr);
        double z = sigd(iz[bb] + biz + hz[bb] + bhz);
        double n = tanh(in_[bb] + bin + r * (hn_[bb] + bhn));
        float hold = h_in[(size_t)b * 512 + j];
        h_out[(size_t)b * 512 + j] = (float)((1.0 - z) * n + z * (double)hold);
    }
}

// ---------------------------------------------------------------------------
// Final reduction (round-2 proven): loss, acc, all_acc.
// ---------------------------------------------------------------------------
__global__ __launch_bounds__(256) void finalize_k(
    const float* __restrict__ nll, const float* __restrict__ inference,
    const int* __restrict__ target, float* __restrict__ out3)
{
    const int tid = threadIdx.x;
    int wrong = 0;
    double match = 0.0;
    const int b = tid;
    for (int t = 0; t < T; ++t) {
        float inf = inference[t * B + b];
        float tg = (float)target[t * B + b];
        bool ok = (inf == tg);
        match += ok ? 1.0 : 0.0;
        wrong |= !ok;
    }
    double lsum = 0.0;
    for (int i = tid; i < T * B; i += 256) lsum += (double)nll[i];

    __shared__ double sl[256], sm_[256], sa[256];
    sl[tid] = lsum; sm_[tid] = match; sa[tid] = wrong ? 0.0 : 1.0;
    __syncthreads();
    for (int off = 128; off > 0; off >>= 1) {
        if (tid < off) {
            sl[tid] += sl[tid + off];
            sm_[tid] += sm_[tid + off];
            sa[tid] += sa[tid + off];
        }
        __syncthreads();
    }
    if (tid == 0) {
        out3[0] = (float)(sl[0] / (double)(T * B));
        out3[1] = (float)(sa[0] / (double)B);
        out3[2] = (float)(sm_[0] / (double)(T * B));
    }
}

// ---------------------------------------------------------------------------
extern "C" void kernel_launch(void* const* d_in, const int* in_sizes, int n_in,
                              void* d_out, int out_size, void* d_ws, size_t ws_size,
                              hipStream_t stream)
{
    const int*   input_seq  = (const int*)d_in[0];
    const int*   input_len  = (const int*)d_in[1];
    const int*   target_seq = (const int*)d_in[2];
    const float* enc_embed  = (const float*)d_in[3];
    const float* enc_Wih    = (const float*)d_in[4];
    const float* enc_Whh    = (const float*)d_in[5];
    const float* enc_bih    = (const float*)d_in[6];
    const float* enc_bhh    = (const float*)d_in[7];
    const float* att_W      = (const float*)d_in[8];
    const float* att_b      = (const float*)d_in[9];
    const float* dec_embed  = (const float*)d_in[10];
    const float* dec_Wih    = (const float*)d_in[11];
    const float* dec_Whh    = (const float*)d_in[12];
    const float* dec_bih    = (const float*)d_in[13];
    const float* dec_bhh    = (const float*)d_in[14];
    const float* mlp_W      = (const float*)d_in[15];
    const float* mlp_b      = (const float*)d_in[16];
    const float* out_W      = (const float*)d_in[17];
    const float* out_b      = (const float*)d_in[18];

    float* out = (float*)d_out;   // [inference (T*B) | loss | acc | all_acc]

    float* gi_tab  = (float*)d_ws;                   // (V, 3H)
    float* mlp_tab = gi_tab + (size_t)VOC * G3;      // (V, H)
    float* h0      = mlp_tab + (size_t)VOC * Hh;     // (B, H)
    float* h1      = h0 + (size_t)B * Hh;
    float* ahb     = h1 + (size_t)B * Hh;
    float* xb      = ahb + (size_t)B * Hh;
    float* lgb     = xb + (size_t)B * Hh;
    float* nllb    = lgb + (size_t)B * Hh;           // (T, B)
    float* enc_out = nllb + (size_t)T * B;           // (S, B, H) ~100 MB

    hipMemsetAsync(h0, 0, (size_t)B * Hh * sizeof(float), stream);

    // Precompute tables:
    // gi_tab[v]  = enc_embed[v] @ enc_Wih.T + enc_bih
    gemm_at<<<dim3(48, 16), 256, 0, stream>>>(
        enc_embed, enc_Wih, 512, 0, enc_bih, gi_tab, G3);
    // mlp_tab[v] = dec_embed[v] @ mlp_W[:, :512].T + mlp_b
    gemm_at<<<dim3(16, 16), 256, 0, stream>>>(
        dec_embed, mlp_W, 1024, 0, mlp_b, mlp_tab, Hh);

    // Encoder scan (final h lands in h0: s=199 odd writes h0)
    for (int s = 0; s < S; ++s) {
        const float* hc = (s & 1) ? h1 : h0;
        float* hx = (s & 1) ? h0 : h1;
        enc_step<<<dim3(32, 8), 256, 0, stream>>>(
            hc, hx, gi_tab, input_seq, input_len, enc_Whh, enc_bhh, s, enc_out);
    }

    // Decoder scan: t = 0..T; at t==T only logits(h_T) + softmax(T-1) remain.
    for (int t = 0; t <= T; ++t) {
        const float* hc = (t & 1) ? h1 : h0;
        float* hx = (t & 1) ? h0 : h1;
        gemm_dual<<<dim3(32, 8), 256, 0, stream>>>(
            hc, att_W, att_b, out_W, out_b, ahb, lgb);
        attn_x_softmax<<<dim3(2 * B), 256, 0, stream>>>(
            enc_out, ahb, mlp_W, mlp_tab, input_len, target_seq,
            lgb, t, xb, nllb, out);
        if (t < T) {
            dec_gru<<<dim3(32, 8), 256, 0, stream>>>(
                xb, hc, dec_Wih, dec_Whh, dec_bih, dec_bhh, hx);
        }
    }

    finalize_k<<<dim3(1), 256, 0, stream>>>(nllb, out, target_seq, out + (size_t)T * B);
}

// Round 6
// 33177.988 us; speedup vs baseline: 4.3877x; 1.3510x over previous
//
#include <hip/hip_runtime.h>
#include <math.h>

// Problem constants
#define B 256
#define Hh 512
#define S 200
#define T 200
#define VOC 512
#define G3 1536
#define PAD 36

// fp64 helpers: inner-product math in double, tensor boundaries quantized fp32.
struct d4 { double x, y, z, w; };
__device__ __forceinline__ d4 tod4(const float4 a) {
    d4 r; r.x = a.x; r.y = a.y; r.z = a.z; r.w = a.w; return r;
}
__device__ __forceinline__ double dotd(const d4& a, const d4& b) {
    return a.x * b.x + a.y * b.y + a.z * b.z + a.w * b.w;
}
__device__ __forceinline__ double sigd(double x) { return 1.0 / (1.0 + exp(-x)); }

// ---------------------------------------------------------------------------
// Table-precompute GEMM (round-2 proven): C[m,j] = sum_k A[m,k]*W[j*ldw+woff+k]
//                                          + bias[j].
// ---------------------------------------------------------------------------
__global__ __launch_bounds__(256) void gemm_at(
    const float* __restrict__ A,
    const float* __restrict__ W, int ldw, int woff,
    const float* __restrict__ bias,
    float* __restrict__ C, int ldc)
{
    __shared__ float As[32][PAD];
    __shared__ float Ws[32][PAD];
    const int tid = threadIdx.x;
    const int tx = tid & 15, ty = tid >> 4;
    const int j0 = blockIdx.x * 32, m0 = blockIdx.y * 32;
    const int lr = tid >> 3, lc = (tid & 7) * 4;

    double acc00 = 0.0, acc01 = 0.0, acc10 = 0.0, acc11 = 0.0;

    for (int k0 = 0; k0 < 512; k0 += 32) {
        float4 av = *(const float4*)(A + (size_t)(m0 + lr) * 512 + k0 + lc);
        float4 wv = *(const float4*)(W + (size_t)(j0 + lr) * ldw + woff + k0 + lc);
        __syncthreads();
        *(float4*)&As[lr][lc] = av;
        *(float4*)&Ws[lr][lc] = wv;
        __syncthreads();
#pragma unroll
        for (int kk = 0; kk < 32; kk += 4) {
            d4 a0 = tod4(*(const float4*)&As[ty][kk]);
            d4 a1 = tod4(*(const float4*)&As[ty + 16][kk]);
            d4 b0 = tod4(*(const float4*)&Ws[tx][kk]);
            d4 b1 = tod4(*(const float4*)&Ws[tx + 16][kk]);
            acc00 += dotd(a0, b0);
            acc01 += dotd(a0, b1);
            acc10 += dotd(a1, b0);
            acc11 += dotd(a1, b1);
        }
    }
    const int ms[2] = { m0 + ty, m0 + ty + 16 };
    const int js[2] = { j0 + tx, j0 + tx + 16 };
    double accs[2][2] = { { acc00, acc01 }, { acc10, acc11 } };
#pragma unroll
    for (int mi = 0; mi < 2; ++mi)
#pragma unroll
        for (int ji = 0; ji < 2; ++ji) {
            int m = ms[mi], j = js[ji];
            C[(size_t)m * ldc + j] = (float)(accs[mi][ji] + (double)bias[j]);
        }
}

// ---------------------------------------------------------------------------
// Encoder GRU step, 512 threads (2 waves/SIMD), k-chunk 64, early-out.
// Grid (32, 8): j0 = bx*16, b0 = by*32. Thread: j_l = tid&15, b_l = tid>>4.
// Per-output k-ascending fp64 accumulation — bitwise identical to round 2.
// ---------------------------------------------------------------------------
__global__ __launch_bounds__(512) void enc_step(
    const float* __restrict__ h_in, float* __restrict__ h_out,
    const float* __restrict__ gi_tab, const int* __restrict__ iseq,
    const int* __restrict__ ilen, const float* __restrict__ Whh,
    const float* __restrict__ bhh, int s, float* __restrict__ enc_out)
{
    __shared__ float Hs[32][68];
    __shared__ float Ws[48][68];
    const int tid = threadIdx.x;
    const int j_l = tid & 15, b_l = tid >> 4;
    const int j0 = blockIdx.x * 16, b0 = blockIdx.y * 32;
    const int j = j0 + j_l, b = b0 + b_l;

    // block-uniform early-out: whole tile past its lengths -> copy + zero
    int ml = 0;
    for (int i = 0; i < 32; ++i) ml = max(ml, ilen[b0 + i]);
    if (s >= ml) {
        h_out[(size_t)b * 512 + j] = h_in[(size_t)b * 512 + j];
        enc_out[((size_t)s * B + b) * 512 + j] = 0.f;
        return;
    }

    double ar = 0.0, az = 0.0, an = 0.0;
    for (int kt = 0; kt < 512; kt += 64) {
        __syncthreads();
        {
            int row = tid >> 4, c4 = (tid & 15) * 4;
            *(float4*)&Hs[row][c4] =
                *(const float4*)(h_in + (size_t)(b0 + row) * 512 + kt + c4);
            for (int idx = tid; idx < 768; idx += 512) {
                int r = idx >> 4, cc = (idx & 15) * 4;
                int g = r >> 4, jj = r & 15;
                *(float4*)&Ws[r][cc] =
                    *(const float4*)(Whh + (size_t)(g * 512 + j0 + jj) * 512 + kt + cc);
            }
        }
        __syncthreads();
#pragma unroll
        for (int kk = 0; kk < 64; kk += 4) {
            d4 hv = tod4(*(const float4*)&Hs[b_l][kk]);
            ar += dotd(hv, tod4(*(const float4*)&Ws[j_l][kk]));
            az += dotd(hv, tod4(*(const float4*)&Ws[16 + j_l][kk]));
            an += dotd(hv, tod4(*(const float4*)&Ws[32 + j_l][kk]));
        }
    }

    float hold = h_in[(size_t)b * 512 + j];
    float hnew = hold;
    if (s < ilen[b]) {
        int tok = iseq[s * B + b];
        const float* gi = gi_tab + (size_t)tok * G3;
        double r = sigd((double)gi[j] + ar + (double)bhh[j]);
        double z = sigd((double)gi[512 + j] + az + (double)bhh[512 + j]);
        double n = tanh((double)gi[1024 + j] + r * (an + (double)bhh[1024 + j]));
        hnew = (float)((1.0 - z) * n + z * (double)hold);
        enc_out[((size_t)s * B + b) * 512 + j] = hnew;
    } else {
        enc_out[((size_t)s * B + b) * 512 + j] = 0.f;
    }
    h_out[(size_t)b * 512 + j] = hnew;
}

// ---------------------------------------------------------------------------
// F1 "proj": dual GEMM over stacked rows [att_W(0..511); out_W(512..1023)],
// 512 threads (2 waves/SIMD), k-chunk 64. Grid (32, 8): R0 = bx*32, m0 = by*32.
// Thread: tx = tid&15 (rows tx, tx+16), ty = tid>>4 (m). At t==T the ah half
// is skipped (only logits of h_T are needed).
// ---------------------------------------------------------------------------
__global__ __launch_bounds__(512) void proj(
    const float* __restrict__ h,
    const float* __restrict__ att_W, const float* __restrict__ att_b,
    const float* __restrict__ out_W, const float* __restrict__ out_b,
    float* __restrict__ ah, float* __restrict__ logits, int t)
{
    __shared__ float As[32][68];
    __shared__ float Ws[32][68];
    const int tid = threadIdx.x;
    const int tx = tid & 15, ty = tid >> 4;
    const int R0 = blockIdx.x * 32, m0 = blockIdx.y * 32;
    const bool is_att = (R0 < 512);
    if (is_att && t >= T) return;   // block-uniform

    double a0 = 0.0, a1 = 0.0;
    for (int kt = 0; kt < 512; kt += 64) {
        __syncthreads();
        {
            int row = tid >> 4, c4 = (tid & 15) * 4;
            *(float4*)&As[row][c4] =
                *(const float4*)(h + (size_t)(m0 + row) * 512 + kt + c4);
            int R = R0 + row;
            const float* ws = is_att ? (att_W + (size_t)R * 512)
                                     : (out_W + (size_t)(R - 512) * 512);
            *(float4*)&Ws[row][c4] = *(const float4*)(ws + kt + c4);
        }
        __syncthreads();
#pragma unroll
        for (int kk = 0; kk < 64; kk += 4) {
            d4 av = tod4(*(const float4*)&As[ty][kk]);
            a0 += dotd(av, tod4(*(const float4*)&Ws[tx][kk]));
            a1 += dotd(av, tod4(*(const float4*)&Ws[16 + tx][kk]));
        }
    }

    const int m = m0 + ty;
    const int Ra = R0 + tx, Rb = R0 + tx + 16;
    if (is_att) {
        double v0 = a0 + (double)att_b[Ra]; if (v0 < 0.0) v0 = 0.0;
        double v1 = a1 + (double)att_b[Rb]; if (v1 < 0.0) v1 = 0.0;
        ah[(size_t)m * 512 + Ra] = (float)v0;
        ah[(size_t)m * 512 + Rb] = (float)v1;
    } else {
        logits[(size_t)m * 512 + (Ra - 512)] = (float)(a0 + (double)out_b[Ra - 512]);
        logits[(size_t)m * 512 + (Rb - 512)] = (float)(a1 + (double)out_b[Rb - 512]);
    }
}

// ---------------------------------------------------------------------------
// F2: blocks 0..255  -> attention (truncated + analytic zero tail) + x via
//                       quad-per-row matvec (coalesced 64B fetches) [t<T]
//     blocks 256..511-> softmax/argmax/nll for step t-1             [t>=1]
// ---------------------------------------------------------------------------
__global__ __launch_bounds__(256) void attn_x_softmax(
    const float* __restrict__ enc_out, const float* __restrict__ ah,
    const float* __restrict__ mlp_W, const float* __restrict__ mlp_tab,
    const int* __restrict__ input_len, const int* __restrict__ target_seq,
    const float* __restrict__ logits, int t,
    float* __restrict__ xbuf, float* __restrict__ nll,
    float* __restrict__ inference)
{
    const int bid = blockIdx.x, tid = threadIdx.x;

    if (bid < B) {
        if (t >= T) return;
        __shared__ float scx[4][512];
        __shared__ double sml[8];
        __shared__ float ctxl[512];
        const int b = bid;
        const int wave = tid >> 6, lane = tid & 63;
        const int len = input_len[b];
        const float* ahb = ah + (size_t)b * 512;
        d4 aa1 = tod4(*(const float4*)(ahb + lane * 4));
        d4 aa2 = tod4(*(const float4*)(ahb + 256 + lane * 4));
        double m = -INFINITY, l = 0.0;
        d4 c1 = {0,0,0,0}, c2 = {0,0,0,0};
        for (int s = wave; s < len; s += 4) {
            const float* row = enc_out + ((size_t)s * B + b) * 512;
            d4 e1 = tod4(*(const float4*)(row + lane * 4));
            d4 e2 = tod4(*(const float4*)(row + 256 + lane * 4));
            double p = dotd(e1, aa1) + dotd(e2, aa2);
#pragma unroll
            for (int off = 32; off >= 1; off >>= 1) p += __shfl_xor(p, off, 64);
            double mn = fmax(m, p);
            double sc = (m == mn) ? 1.0 : exp(m - mn);   // exp(0)==1 exactly
            double w = exp(p - mn);
            l = l * sc + w;
            c1.x = c1.x * sc + w * e1.x; c1.y = c1.y * sc + w * e1.y;
            c1.z = c1.z * sc + w * e1.z; c1.w = c1.w * sc + w * e1.w;
            c2.x = c2.x * sc + w * e2.x; c2.y = c2.y * sc + w * e2.y;
            c2.z = c2.z * sc + w * e2.z; c2.w = c2.w * sc + w * e2.w;
            m = mn;
        }
        if (lane == 0) { sml[wave] = m; sml[4 + wave] = l; }
        *(float4*)&scx[wave][lane * 4] =
            make_float4((float)c1.x, (float)c1.y, (float)c1.z, (float)c1.w);
        *(float4*)&scx[wave][256 + lane * 4] =
            make_float4((float)c2.x, (float)c2.y, (float)c2.z, (float)c2.w);
        __syncthreads();
        double M = fmax(fmax(sml[0], sml[1]), fmax(sml[2], sml[3]));
        if (len < S) M = fmax(M, 0.0);   // zero rows participate in softmax
        double w0 = exp(sml[0] - M), w1x = exp(sml[1] - M);
        double w2x = exp(sml[2] - M), w3 = exp(sml[3] - M);
        double L = sml[4] * w0 + sml[5] * w1x + sml[6] * w2x + sml[7] * w3
                 + (double)(S - len) * exp(0.0 - M);   // analytic zero tail
        for (int jj = tid; jj < 512; jj += 256) {
            double v = (double)scx[0][jj] * w0 + (double)scx[1][jj] * w1x
                     + (double)scx[2][jj] * w2x + (double)scx[3][jj] * w3;
            ctxl[jj] = (float)(v / L);   // fp32 quantization boundary (as ref)
        }
        __syncthreads();

        // x = tanh(mlp_tab[tok] + ctx @ mlpW2.T): quad-per-row, k split 4-way,
        // 2-step shfl reduce. Wave load = 16 rows x 64B contiguous.
        const int tok = (t == 0) ? 1 : target_seq[(t - 1) * B + b];
        const int q = tid & 3;
        const int rbase = tid >> 2;                 // 0..63
#pragma unroll
        for (int pass = 0; pass < 8; ++pass) {
            const int jr = pass * 64 + rbase;
            const float* wr = mlp_W + (size_t)jr * 1024 + 512;
            double a = 0.0;
            for (int k = q * 4; k < 512; k += 16) {
                a += dotd(tod4(*(const float4*)&ctxl[k]),
                          tod4(*(const float4*)(wr + k)));
            }
            a += __shfl_xor(a, 1, 64);
            a += __shfl_xor(a, 2, 64);
            if (q == 0)
                xbuf[(size_t)b * 512 + jr] =
                    (float)tanh((double)mlp_tab[(size_t)tok * 512 + jr] + a);
        }
    } else {
        if (t < 1) return;
        __shared__ float red_f[256];
        __shared__ double red_d[256];
        __shared__ int red_i[256];
        const int sb = bid - B;
        const float* lg = logits + (size_t)sb * 512;
        const float l0 = lg[tid], l1 = lg[256 + tid];
        red_f[tid] = fmaxf(l0, l1);
        __syncthreads();
        for (int off = 128; off > 0; off >>= 1) {
            if (tid < off) red_f[tid] = fmaxf(red_f[tid], red_f[tid + off]);
            __syncthreads();
        }
        const double mx = (double)red_f[0];
        __syncthreads();
        const double e0 = exp((double)l0 - mx), e1 = exp((double)l1 - mx);
        red_d[tid] = e0 + e1;
        __syncthreads();
        for (int off = 128; off > 0; off >>= 1) {
            if (tid < off) red_d[tid] += red_d[tid + off];
            __syncthreads();
        }
        const double Z = red_d[0];
        __syncthreads();
        const float p0 = (float)(e0 / Z), p1 = (float)(e1 / Z);
        float v; int idx;
        if (p0 >= p1) { v = p0; idx = tid; } else { v = p1; idx = 256 + tid; }
        red_f[tid] = v; red_i[tid] = idx;
        __syncthreads();
        for (int off = 128; off > 0; off >>= 1) {
            if (tid < off) {
                float ov = red_f[tid + off]; int oi = red_i[tid + off];
                if (ov > red_f[tid] || (ov == red_f[tid] && oi < red_i[tid])) {
                    red_f[tid] = ov; red_i[tid] = oi;
                }
            }
            __syncthreads();
        }
        if (tid == 0) {
            int tg = target_seq[(t - 1) * B + sb];
            float pt = (float)(exp((double)lg[tg] - mx) / Z);
            pt = fmaxf(pt, 1e-10f);
            nll[(t - 1) * B + sb] = (float)(-log((double)pt));
            inference[(t - 1) * B + sb] = (float)red_i[0];
        }
    }
}

// ---------------------------------------------------------------------------
// Decoder GRU: grid (32,16) = 512 blocks x 256 thr (16b x 16j tile, 1 output
// per thread, 18.4 KB LDS -> 2 blocks/CU = 8 waves/CU). k-chunk 32.
// Per-output k-ascending fp64 accumulation — bitwise identical to round 2.
// ---------------------------------------------------------------------------
__global__ __launch_bounds__(256) void dec_gru(
    const float* __restrict__ x, const float* __restrict__ h_in,
    const float* __restrict__ Wih, const float* __restrict__ Whh,
    const float* __restrict__ bih, const float* __restrict__ bhh,
    float* __restrict__ h_out)
{
    __shared__ float Xs[16][36];
    __shared__ float Hs2[16][36];
    __shared__ float Wi[48][36];
    __shared__ float Wh[48][36];
    const int tid = threadIdx.x;
    const int j_l = tid & 15, b_l = tid >> 4;
    const int j0 = blockIdx.x * 16, b0 = blockIdx.y * 16;
    const int j = j0 + j_l, b = b0 + b_l;

    double air = 0, aiz = 0, ain = 0, ahr = 0, ahz = 0, ahn = 0;
    for (int kt = 0; kt < 512; kt += 32) {
        __syncthreads();
        for (int idx = tid; idx < 1024; idx += 256) {
            if (idx < 128) {
                int row = idx >> 3, c4 = (idx & 7) * 4;
                *(float4*)&Xs[row][c4] =
                    *(const float4*)(x + (size_t)(b0 + row) * 512 + kt + c4);
            } else if (idx < 256) {
                int w = idx - 128; int row = w >> 3, c4 = (w & 7) * 4;
                *(float4*)&Hs2[row][c4] =
                    *(const float4*)(h_in + (size_t)(b0 + row) * 512 + kt + c4);
            } else if (idx < 640) {
                int w = idx - 256; int row = w >> 3, c4 = (w & 7) * 4;
                int g = row >> 4, jj = row & 15;
                *(float4*)&Wi[row][c4] =
                    *(const float4*)(Wih + (size_t)(g * 512 + j0 + jj) * 512 + kt + c4);
            } else {
                int w = idx - 640; int row = w >> 3, c4 = (w & 7) * 4;
                int g = row >> 4, jj = row & 15;
                *(float4*)&Wh[row][c4] =
                    *(const float4*)(Whh + (size_t)(g * 512 + j0 + jj) * 512 + kt + c4);
            }
        }
        __syncthreads();
#pragma unroll
        for (int kk = 0; kk < 32; kk += 4) {
            d4 xv = tod4(*(const float4*)&Xs[b_l][kk]);
            d4 hv = tod4(*(const float4*)&Hs2[b_l][kk]);
            air += dotd(xv, tod4(*(const float4*)&Wi[j_l][kk]));
            aiz += dotd(xv, tod4(*(const float4*)&Wi[16 + j_l][kk]));
            ain += dotd(xv, tod4(*(const float4*)&Wi[32 + j_l][kk]));
            ahr += dotd(hv, tod4(*(const float4*)&Wh[j_l][kk]));
            ahz += dotd(hv, tod4(*(const float4*)&Wh[16 + j_l][kk]));
            ahn += dotd(hv, tod4(*(const float4*)&Wh[32 + j_l][kk]));
        }
    }

    double r = sigd(air + (double)bih[j] + ahr + (double)bhh[j]);
    double z = sigd(aiz + (double)bih[512 + j] + ahz + (double)bhh[512 + j]);
    double n = tanh(ain + (double)bih[1024 + j] + r * (ahn + (double)bhh[1024 + j]));
    float hold = h_in[(size_t)b * 512 + j];
    h_out[(size_t)b * 512 + j] = (float)((1.0 - z) * n + z * (double)hold);
}

// ---------------------------------------------------------------------------
// Final reduction (round-2 proven).
// ---------------------------------------------------------------------------
__global__ __launch_bounds__(256) void finalize_k(
    const float* __restrict__ nll, const float* __restrict__ inference,
    const int* __restrict__ target, float* __restrict__ out3)
{
    const int tid = threadIdx.x;
    int wrong = 0;
    double match = 0.0;
    const int b = tid;
    for (int t = 0; t < T; ++t) {
        float inf = inference[t * B + b];
        float tg = (float)target[t * B + b];
        bool ok = (inf == tg);
        match += ok ? 1.0 : 0.0;
        wrong |= !ok;
    }
    double lsum = 0.0;
    for (int i = tid; i < T * B; i += 256) lsum += (double)nll[i];

    __shared__ double sl[256], sm_[256], sa[256];
    sl[tid] = lsum; sm_[tid] = match; sa[tid] = wrong ? 0.0 : 1.0;
    __syncthreads();
    for (int off = 128; off > 0; off >>= 1) {
        if (tid < off) {
            sl[tid] += sl[tid + off];
            sm_[tid] += sm_[tid + off];
            sa[tid] += sa[tid + off];
        }
        __syncthreads();
    }
    if (tid == 0) {
        out3[0] = (float)(sl[0] / (double)(T * B));
        out3[1] = (float)(sa[0] / (double)B);
        out3[2] = (float)(sm_[0] / (double)(T * B));
    }
}

// ---------------------------------------------------------------------------
extern "C" void kernel_launch(void* const* d_in, const int* in_sizes, int n_in,
                              void* d_out, int out_size, void* d_ws, size_t ws_size,
                              hipStream_t stream)
{
    const int*   input_seq  = (const int*)d_in[0];
    const int*   input_len  = (const int*)d_in[1];
    const int*   target_seq = (const int*)d_in[2];
    const float* enc_embed  = (const float*)d_in[3];
    const float* enc_Wih    = (const float*)d_in[4];
    const float* enc_Whh    = (const float*)d_in[5];
    const float* enc_bih    = (const float*)d_in[6];
    const float* enc_bhh    = (const float*)d_in[7];
    const float* att_W      = (const float*)d_in[8];
    const float* att_b      = (const float*)d_in[9];
    const float* dec_embed  = (const float*)d_in[10];
    const float* dec_Wih    = (const float*)d_in[11];
    const float* dec_Whh    = (const float*)d_in[12];
    const float* dec_bih    = (const float*)d_in[13];
    const float* dec_bhh    = (const float*)d_in[14];
    const float* mlp_W      = (const float*)d_in[15];
    const float* mlp_b      = (const float*)d_in[16];
    const float* out_W      = (const float*)d_in[17];
    const float* out_b      = (const float*)d_in[18];

    float* out = (float*)d_out;   // [inference (T*B) | loss | acc | all_acc]

    float* gi_tab  = (float*)d_ws;                   // (V, 3H)
    float* mlp_tab = gi_tab + (size_t)VOC * G3;      // (V, H)
    float* h0      = mlp_tab + (size_t)VOC * Hh;     // (B, H)
    float* h1      = h0 + (size_t)B * Hh;
    float* ahb     = h1 + (size_t)B * Hh;
    float* xb      = ahb + (size_t)B * Hh;
    float* lgb     = xb + (size_t)B * Hh;
    float* nllb    = lgb + (size_t)B * Hh;           // (T, B)
    float* enc_out = nllb + (size_t)T * B;           // (S, B, H) ~100 MB

    hipMemsetAsync(h0, 0, (size_t)B * Hh * sizeof(float), stream);

    // Precompute tables:
    gemm_at<<<dim3(48, 16), 256, 0, stream>>>(
        enc_embed, enc_Wih, 512, 0, enc_bih, gi_tab, G3);
    gemm_at<<<dim3(16, 16), 256, 0, stream>>>(
        dec_embed, mlp_W, 1024, 0, mlp_b, mlp_tab, Hh);

    // Encoder scan (final h lands in h0: s=199 odd writes h0)
    for (int s = 0; s < S; ++s) {
        const float* hc = (s & 1) ? h1 : h0;
        float* hx = (s & 1) ? h0 : h1;
        enc_step<<<dim3(32, 8), 512, 0, stream>>>(
            hc, hx, gi_tab, input_seq, input_len, enc_Whh, enc_bhh, s, enc_out);
    }

    // Decoder scan: t = 0..T; at t==T only logits(h_T) + softmax(T-1) remain.
    for (int t = 0; t <= T; ++t) {
        const float* hc = (t & 1) ? h1 : h0;
        float* hx = (t & 1) ? h0 : h1;
        proj<<<dim3(32, 8), 512, 0, stream>>>(
            hc, att_W, att_b, out_W, out_b, ahb, lgb, t);
        attn_x_softmax<<<dim3(2 * B), 256, 0, stream>>>(
            enc_out, ahb, mlp_W, mlp_tab, input_len, target_seq,
            lgb, t, xb, nllb, out);
        if (t < T) {
            dec_gru<<<dim3(32, 16), 256, 0, stream>>>(
                xb, hc, dec_Wih, dec_Whh, dec_bih, dec_bhh, hx);
        }
    }

    finalize_k<<<dim3(1), 256, 0, stream>>>(nllb, out, target_seq, out + (size_t)T * B);
}